// Round 9
// baseline (87.784 us; speedup 1.0000x reference)
//
#include <hip/hip_runtime.h>

#define NUM_V 100000
#define NUM_R 1000
#define ARITY 3
#define DD 128
#define DI 192   /* D + I */
#define HH 128
#define BB 4096
#define NN 64

typedef __attribute__((ext_vector_type(4))) float f32x4;
typedef __attribute__((ext_vector_type(8))) _Float16 half8;
typedef __attribute__((ext_vector_type(2))) _Float16 half2v;

// async global->LDS, 16B per lane; LDS dest is wave-uniform base, HW adds lane*16
__device__ inline void gload16(const void* g, void* lds) {
    __builtin_amdgcn_global_load_lds(
        (const __attribute__((address_space(1))) unsigned int*)g,
        (__attribute__((address_space(3))) unsigned int*)lds, 16, 0, 0);
}

// ---------------- Fused prep: proj(R) | wfrag(WV, f16) | pe ------------------
// blocks 0..31  : proj body (RWh = R @ WR + bR -> fp16)
// blocks 32..79 : wfrag body (f16 W fragments, MFMA layout, single table)
// block  80     : peProd[h] = prod_a (P[a]@WP + bP)[h]
__global__ __launch_bounds__(256) void prep_kernel(
    const float* __restrict__ R, const float* __restrict__ WR, const float* __restrict__ bR,
    _Float16* __restrict__ RWh,
    const float* __restrict__ WV, unsigned short* __restrict__ wf,
    const float* __restrict__ P, const float* __restrict__ WP, const float* __restrict__ bP,
    float* __restrict__ peProd) {
    const int bid = blockIdx.x;
    const int tid = threadIdx.x;

    if (bid < 32) {
        const int lane = tid & 63;
        const int wave = tid >> 6;
        const int wavesPerGrid = 32 * 4;
        const int waveId = bid * 4 + wave;
        const float2 b2 = ((const float2*)bR)[lane];
        const float2* __restrict__ W2 = (const float2*)WR;
        for (int rowBase0 = waveId * 8; rowBase0 < NUM_R; rowBase0 += wavesPerGrid * 8) {
            const int rowBase = __builtin_amdgcn_readfirstlane(rowBase0);
            float2 acc[8];
#pragma unroll
            for (int r8 = 0; r8 < 8; ++r8) acc[r8] = make_float2(0.f, 0.f);
#pragma unroll 4
            for (int k4 = 0; k4 < DD / 4; ++k4) {
                float4 v[8];
#pragma unroll
                for (int r8 = 0; r8 < 8; ++r8)
                    v[r8] = ((const float4*)(R + (size_t)(rowBase + r8) * DD))[k4];
#pragma unroll
                for (int kk = 0; kk < 4; ++kk) {
                    float2 w = W2[(k4 * 4 + kk) * 64 + lane];
#pragma unroll
                    for (int r8 = 0; r8 < 8; ++r8) {
                        float vv = (kk == 0) ? v[r8].x : (kk == 1) ? v[r8].y : (kk == 2) ? v[r8].z : v[r8].w;
                        acc[r8].x += vv * w.x;
                        acc[r8].y += vv * w.y;
                    }
                }
            }
#pragma unroll
            for (int r8 = 0; r8 < 8; ++r8) {
                if (rowBase + r8 < NUM_R) {
                    half2v h;
                    h.x = (_Float16)(acc[r8].x + b2.x);
                    h.y = (_Float16)(acc[r8].y + b2.y);
                    *(half2v*)(RWh + (size_t)(rowBase + r8) * HH + lane * 2) = h;
                }
            }
        }
    } else if (bid < 80) {
        // ---- wfrag (f16): wf[kstep(6)][ctile(8)][lane(64)][j(8)] ushort(f16 bits)
        if (tid < 64) {
            const int wb = bid - 32;
            const int ks = wb >> 3;  // 0..5
            const int ct = wb & 7;   // 0..7
            const int l = tid;       // 0..63
            const int col = ct * 16 + (l & 15);
            const int k0 = ks * 32 + (l >> 4) * 8;
            size_t base = (size_t)(ks * 8 + ct) * 512;
#pragma unroll
            for (int j = 0; j < 8; ++j) {
                float v = WV[(size_t)(k0 + j) * HH + col];
                wf[base + l * 8 + j] = __builtin_bit_cast(unsigned short, (_Float16)v);
            }
        }
    } else {
        if (tid < HH) {
            int h = tid;
            float prod = 1.0f;
            for (int a = 0; a < ARITY; ++a) {
                float acc = bP[h];
                for (int d = 0; d < DD; ++d) acc += P[a * DD + d] * WP[d * HH + h];
                prod *= acc;
            }
            peProd[h] = prod;
        }
    }
}

// ---------------- Dense-row f16 MFMA GEMM ------------------------------------
// C(fp16) = A @ W + bias. ROOT-CAUSE FIX for the 9-round ~37us invariant:
// every prior variant read each 768B A-row in 128B pieces (density 17%) ->
// HBM burst efficiency ~17% -> fetch pinned at ~1.3-1.9 TB/s regardless of
// schedule (fills on same chip: 6.9 TB/s dense). Here each wave stages its
// ENTIRE 32x192 A-tile (24 KB = one contiguous global region) into a
// wave-private LDS slot with 24 global_load_lds of 1024 contiguous bytes
// each -- full-row dense reads -> row-buffer-friendly -> ~5-6 TB/s.
// Per-row XOR chunk-swizzle (within 128B groups, global reads stay dense;
// involution applied on source offset AND ds_read) since 192%32==0 would be
// a 16-way bank conflict. B register-prefetched from L2 (contiguous 1KB
// loads, 768KB table hot per-XCD). 256 blocks x 6 waves; wave slot s =
// bid+256*wv does tiles s, s+1536, (s+3072 if s<53). Hazards: vmcnt(8)
// drains the 24 stage loads (B0 stays in flight); lgkmcnt(0)+sched_barrier
// at tile top protects the LDS slot from overwrite (rule #18).
__global__ __launch_bounds__(384) void gemm_dense(const float* __restrict__ A,
                                                  const unsigned short* __restrict__ wf,
                                                  const float* __restrict__ bias,
                                                  _Float16* __restrict__ C, int M) {
    __shared__ float atile[6][32 * DI];  // 6 waves x 24 KB = 144 KB

    const int tid = threadIdx.x;
    const int l = tid & 63;
    const int wv = tid >> 6;  // 0..5

    const int slot = blockIdx.x + 256 * wv;   // 0..1535
    const int ntile = (slot < 53) ? 3 : 2;    // 3125 = 53*3 + 1483*2

    float bcol[8];
#pragma unroll
    for (int ct = 0; ct < 8; ++ct) bcol[ct] = bias[ct * 16 + (l & 15)];

    // ---- stage source offsets (floats), computed ONCE (same every tile):
    // instr i, lane l covers LDS chunk p = i*64+l (16B chunks);
    // LDS (row r, chunk-pos cp) holds global chunk (cp ^ (r&7)) of row r.
    int srcoff[24];
#pragma unroll
    for (int i = 0; i < 24; ++i) {
        const int p = i * 64 + l;
        const int r = p / 48;           // 48 chunks (768B) per row
        const int cp = p - r * 48;
        srcoff[i] = r * DI + ((cp ^ (r & 7)) << 2);
    }

    // ---- fragment ds_read base offsets (floats): row R = rt*16+(l&15),
    // global chunk c = ks*8 + 2q + k -> LDS chunk c ^ (R&7); since ks*8 is
    // 8-aligned and the XOR touches only low 3 bits: offset =
    // R*192 + ks*32 + (((2q+k)^(R&7))<<2). ks*32 folds into the immediate.
    int aoffb[2][2];
#pragma unroll
    for (int rt = 0; rt < 2; ++rt) {
        const int Rr = rt * 16 + (l & 15);
        const int q = l >> 4;
#pragma unroll
        for (int k = 0; k < 2; ++k)
            aoffb[rt][k] = Rr * DI + (((2 * q + k) ^ (Rr & 7)) << 2);
    }

    const unsigned short* Bb = wf + l * 8;

    for (int t = 0; t < ntile; ++t) {
        const int tile = slot + t * 1536;
        const int rowbase = tile * 32;
        const float* Aw = A + (size_t)rowbase * DI;

        // protect LDS slot: all previous-tile ds_reads retired before overwrite
        asm volatile("s_waitcnt lgkmcnt(0)" ::: "memory");
        __builtin_amdgcn_sched_barrier(0);

        // stage full tile: 24 x 1024 contiguous bytes (dense rows)
#pragma unroll
        for (int i = 0; i < 24; ++i)
            gload16(Aw + srcoff[i], (char*)&atile[wv][0] + i * 1024);
        __builtin_amdgcn_sched_barrier(0);

        // B(0) prefetch (issued AFTER stage so vmcnt(8) leaves only B0 in flight)
        half8 bh[2][8];
#pragma unroll
        for (int ct = 0; ct < 8; ++ct)
            bh[0][ct] = *(const half8*)(Bb + (size_t)(0 * 8 + ct) * 512);
        __builtin_amdgcn_sched_barrier(0);

        asm volatile("s_waitcnt vmcnt(8)" ::: "memory");  // 24 stage loads done
        __builtin_amdgcn_sched_barrier(0);

        f32x4 acc[2][8];
#pragma unroll
        for (int rt = 0; rt < 2; ++rt)
#pragma unroll
            for (int ct = 0; ct < 8; ++ct) acc[rt][ct] = (f32x4){0.f, 0.f, 0.f, 0.f};

#pragma unroll
        for (int ks = 0; ks < 6; ++ks) {
            // A fragments from LDS (2-way bank alias = free)
            f32x4 av[2][2];
#pragma unroll
            for (int rt = 0; rt < 2; ++rt) {
                av[rt][0] = *(const f32x4*)&atile[wv][aoffb[rt][0] + ks * 32];
                av[rt][1] = *(const f32x4*)&atile[wv][aoffb[rt][1] + ks * 32];
            }
            // next-step B prefetch (compile-time buffer index under unroll)
            if (ks < 5) {
#pragma unroll
                for (int ct = 0; ct < 8; ++ct)
                    bh[(ks + 1) & 1][ct] = *(const half8*)(Bb + (size_t)((ks + 1) * 8 + ct) * 512);
            }
            // fp32 -> f16 convert (16 v_cvt, RNE)
            half8 ah[2];
#pragma unroll
            for (int rt = 0; rt < 2; ++rt) {
                half8 tt;
                tt[0] = (_Float16)av[rt][0].x;
                tt[1] = (_Float16)av[rt][0].y;
                tt[2] = (_Float16)av[rt][0].z;
                tt[3] = (_Float16)av[rt][0].w;
                tt[4] = (_Float16)av[rt][1].x;
                tt[5] = (_Float16)av[rt][1].y;
                tt[6] = (_Float16)av[rt][1].z;
                tt[7] = (_Float16)av[rt][1].w;
                ah[rt] = tt;
            }
#pragma unroll
            for (int ct = 0; ct < 8; ++ct) {
#pragma unroll
                for (int rt = 0; rt < 2; ++rt)
                    acc[rt][ct] = __builtin_amdgcn_mfma_f32_16x16x32_f16(ah[rt], bh[ks & 1][ct], acc[rt][ct], 0, 0, 0);
            }
        }

        // epilogue: full 256B C-lines per wave (col = ct*16 + (l&15))
#pragma unroll
        for (int rt = 0; rt < 2; ++rt) {
            const int rb = rowbase + rt * 16 + (l >> 4) * 4;
#pragma unroll
            for (int j = 0; j < 4; ++j) {
                const int row = rb + j;
                if (row < M) {
#pragma unroll
                    for (int ct = 0; ct < 8; ++ct)
                        C[(size_t)row * HH + ct * 16 + (l & 15)] = (_Float16)(acc[rt][ct][j] + bcol[ct]);
                }
            }
        }
    }
}

// ---------------- Gather - product - neighbor-sum (fp16 tables) --------------
// out[b,h] = peProd[h] * sum_n RWh[r[b,n]][h] * prod_a VWh[e[a,b,n]][h]
__global__ __launch_bounds__(256) void gather_kernel(const int* __restrict__ r,
                                                     const int* __restrict__ e,
                                                     const _Float16* __restrict__ VWh,
                                                     const _Float16* __restrict__ RWh,
                                                     const float* __restrict__ peProd,
                                                     float* __restrict__ out) {
    __shared__ int rIdx[NN];
    __shared__ int eIdx[ARITY][NN];
    __shared__ float4 partial[3][16][2];

    const int b = blockIdx.x;
    const int tid = threadIdx.x;

    if (tid < NN) {
        rIdx[tid] = r[b * NN + tid];
    } else {
        int t = tid - NN;
        eIdx[t >> 6][t & 63] = e[(size_t)(t >> 6) * BB * NN + b * NN + (t & 63)];
    }
    __syncthreads();

    const int lane = tid & 63;
    const int wv = tid >> 6;    // 0..3
    const int q = lane >> 4;    // neighbor sub-slot 0..3
    const int ho = lane & 15;   // h-octet: h = ho*8 .. +8

    float acc8[8];
#pragma unroll
    for (int k = 0; k < 8; ++k) acc8[k] = 0.f;

#pragma unroll
    for (int it = 0; it < 4; ++it) {
        int n = it * 16 + wv * 4 + q;
        half8 rw = *(const half8*)(RWh + (size_t)rIdx[n] * HH + ho * 8);
        half8 v0 = *(const half8*)(VWh + (size_t)eIdx[0][n] * HH + ho * 8);
        half8 v1 = *(const half8*)(VWh + (size_t)eIdx[1][n] * HH + ho * 8);
        half8 v2 = *(const half8*)(VWh + (size_t)eIdx[2][n] * HH + ho * 8);
        half8 p = rw * v0;
        p = p * v1;
        p = p * v2;
#pragma unroll
        for (int k = 0; k < 8; ++k) acc8[k] += (float)p[k];
    }

    // combine the 4 neighbor sub-slots (lane quarters share ho)
#pragma unroll
    for (int k = 0; k < 8; ++k) {
        acc8[k] += __shfl_xor(acc8[k], 16);
        acc8[k] += __shfl_xor(acc8[k], 32);
    }

    if (wv > 0 && lane < 16) {
        partial[wv - 1][ho][0] = make_float4(acc8[0], acc8[1], acc8[2], acc8[3]);
        partial[wv - 1][ho][1] = make_float4(acc8[4], acc8[5], acc8[6], acc8[7]);
    }
    __syncthreads();
    if (wv == 0 && lane < 16) {
        float4 s0 = make_float4(acc8[0], acc8[1], acc8[2], acc8[3]);
        float4 s1 = make_float4(acc8[4], acc8[5], acc8[6], acc8[7]);
#pragma unroll
        for (int g = 0; g < 3; ++g) {
            float4 t0 = partial[g][ho][0], t1 = partial[g][ho][1];
            s0.x += t0.x; s0.y += t0.y; s0.z += t0.z; s0.w += t0.w;
            s1.x += t1.x; s1.y += t1.y; s1.z += t1.z; s1.w += t1.w;
        }
        float4 p0 = ((const float4*)peProd)[ho * 2];
        float4 p1 = ((const float4*)peProd)[ho * 2 + 1];
        ((float4*)(out + (size_t)b * HH))[ho * 2] =
            make_float4(s0.x * p0.x, s0.y * p0.y, s0.z * p0.z, s0.w * p0.w);
        ((float4*)(out + (size_t)b * HH))[ho * 2 + 1] =
            make_float4(s1.x * p1.x, s1.y * p1.y, s1.z * p1.z, s1.w * p1.w);
    }
}

// ---------------- Launch -----------------------------------------------------
extern "C" void kernel_launch(void* const* d_in, const int* in_sizes, int n_in,
                              void* d_out, int out_size, void* d_ws, size_t ws_size,
                              hipStream_t stream) {
    const int* r = (const int*)d_in[0];
    const int* e = (const int*)d_in[1];
    const float* V = (const float*)d_in[2];
    const float* R = (const float*)d_in[3];
    const float* P = (const float*)d_in[4];
    const float* WV = (const float*)d_in[5];
    const float* bV = (const float*)d_in[6];
    const float* WR = (const float*)d_in[7];
    const float* bR = (const float*)d_in[8];
    const float* WP = (const float*)d_in[9];
    const float* bP = (const float*)d_in[10];
    float* out = (float*)d_out;

    // ws layout: VWh [NUM_V,H] fp16 | RWh [NUM_R,H] fp16 | peProd [H] f32 | Wfrag 48 KB (f16)
    _Float16* VWh = (_Float16*)d_ws;
    _Float16* RWh = VWh + (size_t)NUM_V * HH;
    float* peProd = (float*)(RWh + (size_t)NUM_R * HH);
    unsigned short* wfrag = (unsigned short*)(peProd + HH);

    prep_kernel<<<81, 256, 0, stream>>>(R, WR, bR, RWh, WV, wfrag, P, WP, bP, peProd);
    gemm_dense<<<256, 384, 0, stream>>>(V, wfrag, bV, VWh, NUM_V);
    gather_kernel<<<BB, 256, 0, stream>>>(r, e, VWh, RWh, peProd, out);
}

// Round 10
// 68.714 us; speedup vs baseline: 1.2775x; 1.2775x over previous
//
#include <hip/hip_runtime.h>

#define NUM_V 100000
#define NUM_R 1000
#define ARITY 3
#define DD 128
#define DI 192   /* D + I */
#define HH 128
#define BB 4096
#define NN 64

typedef __attribute__((ext_vector_type(4))) float f32x4;
typedef __attribute__((ext_vector_type(8))) _Float16 half8;
typedef __attribute__((ext_vector_type(2))) _Float16 half2v;

// async global->LDS, 16B per lane; LDS dest is wave-uniform base, HW adds lane*16
__device__ inline void gload16(const void* g, void* lds) {
    __builtin_amdgcn_global_load_lds(
        (const __attribute__((address_space(1))) unsigned int*)g,
        (__attribute__((address_space(3))) unsigned int*)lds, 16, 0, 0);
}

// ---------------- Fused prep: proj(R) | wfrag(WV, f16) | pe ------------------
// blocks 0..31  : proj body (RWh = R @ WR + bR -> fp16)
// blocks 32..79 : wfrag body (f16 W fragments, MFMA layout, single table)
// block  80     : peProd[h] = prod_a (P[a]@WP + bP)[h]
__global__ __launch_bounds__(256) void prep_kernel(
    const float* __restrict__ R, const float* __restrict__ WR, const float* __restrict__ bR,
    _Float16* __restrict__ RWh,
    const float* __restrict__ WV, unsigned short* __restrict__ wf,
    const float* __restrict__ P, const float* __restrict__ WP, const float* __restrict__ bP,
    float* __restrict__ peProd) {
    const int bid = blockIdx.x;
    const int tid = threadIdx.x;

    if (bid < 32) {
        const int lane = tid & 63;
        const int wave = tid >> 6;
        const int wavesPerGrid = 32 * 4;
        const int waveId = bid * 4 + wave;
        const float2 b2 = ((const float2*)bR)[lane];
        const float2* __restrict__ W2 = (const float2*)WR;
        for (int rowBase0 = waveId * 8; rowBase0 < NUM_R; rowBase0 += wavesPerGrid * 8) {
            const int rowBase = __builtin_amdgcn_readfirstlane(rowBase0);
            float2 acc[8];
#pragma unroll
            for (int r8 = 0; r8 < 8; ++r8) acc[r8] = make_float2(0.f, 0.f);
#pragma unroll 4
            for (int k4 = 0; k4 < DD / 4; ++k4) {
                float4 v[8];
#pragma unroll
                for (int r8 = 0; r8 < 8; ++r8)
                    v[r8] = ((const float4*)(R + (size_t)(rowBase + r8) * DD))[k4];
#pragma unroll
                for (int kk = 0; kk < 4; ++kk) {
                    float2 w = W2[(k4 * 4 + kk) * 64 + lane];
#pragma unroll
                    for (int r8 = 0; r8 < 8; ++r8) {
                        float vv = (kk == 0) ? v[r8].x : (kk == 1) ? v[r8].y : (kk == 2) ? v[r8].z : v[r8].w;
                        acc[r8].x += vv * w.x;
                        acc[r8].y += vv * w.y;
                    }
                }
            }
#pragma unroll
            for (int r8 = 0; r8 < 8; ++r8) {
                if (rowBase + r8 < NUM_R) {
                    half2v h;
                    h.x = (_Float16)(acc[r8].x + b2.x);
                    h.y = (_Float16)(acc[r8].y + b2.y);
                    *(half2v*)(RWh + (size_t)(rowBase + r8) * HH + lane * 2) = h;
                }
            }
        }
    } else if (bid < 80) {
        // ---- wfrag (f16): wf[kstep(6)][ctile(8)][lane(64)][j(8)] ushort(f16 bits)
        if (tid < 64) {
            const int wb = bid - 32;
            const int ks = wb >> 3;  // 0..5
            const int ct = wb & 7;   // 0..7
            const int l = tid;       // 0..63
            const int col = ct * 16 + (l & 15);
            const int k0 = ks * 32 + (l >> 4) * 8;
            size_t base = (size_t)(ks * 8 + ct) * 512;
#pragma unroll
            for (int j = 0; j < 8; ++j) {
                float v = WV[(size_t)(k0 + j) * HH + col];
                wf[base + l * 8 + j] = __builtin_bit_cast(unsigned short, (_Float16)v);
            }
        }
    } else {
        if (tid < HH) {
            int h = tid;
            float prod = 1.0f;
            for (int a = 0; a < ARITY; ++a) {
                float acc = bP[h];
                for (int d = 0; d < DD; ++d) acc += P[a * DD + d] * WP[d * HH + h];
                prod *= acc;
            }
            peProd[h] = prod;
        }
    }
}

// ---------------- B-resident f16 GEMM, wave-count-maximized ------------------
// C(fp16) = A @ W + bias. Ten-round synthesis: delivered A-bandwidth tracks
// the NUMBER of A-streaming waves (~0.7 GB/s per wave under full queues),
// not per-wave pipeline depth, not burst density (R9 refuted), not schedule
// choreography (R1-R8 refuted). m13's 6.3 TB/s copy runs ~8K waves; our
// gemms ran ~3.3K. Fix: halve the per-wave tile to 16 rows and double the
// grid -> 6250 active streaming waves (24.4/CU, was 12.2), 2 blocks/CU
// (LDS 2 x 48 KB = 96 <= 160; VGPR ~95 at 7 waves/SIMD). Everything else is
// the proven round-7 structure: W table (48 KB f16) LDS-resident, one
// barrier, 3-deep A register prefetch, straight-line compiler-counted waits.
__global__ __launch_bounds__(832, 6) void gemm_bres(const float* __restrict__ A,
                                                    const unsigned short* __restrict__ wf,
                                                    const float* __restrict__ bias,
                                                    _Float16* __restrict__ C, int M) {
    __shared__ unsigned short bsm[24576];  // 48 KB, byte-identical to wfrag layout

    const int tid = threadIdx.x;
    const int l = tid & 63;
    const int wv = tid >> 6;  // 0..12

    const int tile = wv * 512 + blockIdx.x;  // 0..6655, each hit exactly once
    const int rowbase = tile * 16;
    const bool active = rowbase < M;  // wave-uniform (M = 6250*16 exactly)

    // bias per col-tile
    float bcol[8];
#pragma unroll
    for (int ct = 0; ct < 8; ++ct) bcol[ct] = bias[ct * 16 + (l & 15)];

    // A fragment pointer: row = rowbase + (l&15), k-base (l>>4)*8
    const float* aptr;
    {
        int rr = rowbase + (l & 15);
        if (rr >= M) rr = M - 1;
        aptr = A + (size_t)rr * DI + (l >> 4) * 8;
    }

    f32x4 acc[8];
#pragma unroll
    for (int ct = 0; ct < 8; ++ct) acc[ct] = (f32x4){0.f, 0.f, 0.f, 0.f};

    float4 va[3][2];  // [buf][half] -- 3-deep pipeline, static indices
#define LOAD_A(buf, ks)                                   \
    do {                                                  \
        va[buf][0] = *(const float4*)(aptr + (ks) * 32);  \
        va[buf][1] = *(const float4*)(aptr + (ks) * 32 + 4); \
    } while (0)

    // prologue A loads first (start HBM/L3 traffic earliest)
    if (active) {
        LOAD_A(0, 0);
        LOAD_A(1, 1);
    }

    // ---- stage f16 W table: waves 0..11 stage 4 KB each = 48 KB, linear
    if (wv < 12) {
#pragma unroll
        for (int i = 0; i < 4; ++i) {
            const int off = wv * 4096 + i * 1024;  // bytes, wave-uniform dest
            gload16((const char*)wf + off + l * 16, (char*)bsm + off);
        }
    }

    __syncthreads();  // the ONLY barrier: publishes LDS W-table to all waves
    if (!active) return;

#pragma unroll
    for (int ks = 0; ks < 6; ++ks) {
        const int cur = ks % 3;
        if (ks < 4) LOAD_A((ks + 2) % 3, ks + 2);

        // fp32 -> f16 convert of current A fragment (8 v_cvt, RNE)
        half8 ah;
        {
            half8 t;
            t[0] = (_Float16)va[cur][0].x;
            t[1] = (_Float16)va[cur][0].y;
            t[2] = (_Float16)va[cur][0].z;
            t[3] = (_Float16)va[cur][0].w;
            t[4] = (_Float16)va[cur][1].x;
            t[5] = (_Float16)va[cur][1].y;
            t[6] = (_Float16)va[cur][1].z;
            t[7] = (_Float16)va[cur][1].w;
            ah = t;
        }

#pragma unroll
        for (int ct = 0; ct < 8; ++ct) {
            const int fb = (ks * 8 + ct) * 512;  // ushort index of fragment
            half8 bh = *(const half8*)&bsm[fb + l * 8];
            acc[ct] = __builtin_amdgcn_mfma_f32_16x16x32_f16(ah, bh, acc[ct], 0, 0, 0);
        }
    }
#undef LOAD_A

    // epilogue: wave writes full 256B C-lines (col = ct*16 + (l&15))
    {
        const int rb = rowbase + (l >> 4) * 4;
#pragma unroll
        for (int j = 0; j < 4; ++j) {
            const int row = rb + j;
            if (row < M) {
#pragma unroll
                for (int ct = 0; ct < 8; ++ct)
                    C[(size_t)row * HH + ct * 16 + (l & 15)] = (_Float16)(acc[ct][j] + bcol[ct]);
            }
        }
    }
}

// ---------------- Gather - product - neighbor-sum (fp16 tables) --------------
// out[b,h] = peProd[h] * sum_n RWh[r[b,n]][h] * prod_a VWh[e[a,b,n]][h]
__global__ __launch_bounds__(256) void gather_kernel(const int* __restrict__ r,
                                                     const int* __restrict__ e,
                                                     const _Float16* __restrict__ VWh,
                                                     const _Float16* __restrict__ RWh,
                                                     const float* __restrict__ peProd,
                                                     float* __restrict__ out) {
    __shared__ int rIdx[NN];
    __shared__ int eIdx[ARITY][NN];
    __shared__ float4 partial[3][16][2];

    const int b = blockIdx.x;
    const int tid = threadIdx.x;

    if (tid < NN) {
        rIdx[tid] = r[b * NN + tid];
    } else {
        int t = tid - NN;
        eIdx[t >> 6][t & 63] = e[(size_t)(t >> 6) * BB * NN + b * NN + (t & 63)];
    }
    __syncthreads();

    const int lane = tid & 63;
    const int wv = tid >> 6;    // 0..3
    const int q = lane >> 4;    // neighbor sub-slot 0..3
    const int ho = lane & 15;   // h-octet: h = ho*8 .. +8

    float acc8[8];
#pragma unroll
    for (int k = 0; k < 8; ++k) acc8[k] = 0.f;

#pragma unroll
    for (int it = 0; it < 4; ++it) {
        int n = it * 16 + wv * 4 + q;
        half8 rw = *(const half8*)(RWh + (size_t)rIdx[n] * HH + ho * 8);
        half8 v0 = *(const half8*)(VWh + (size_t)eIdx[0][n] * HH + ho * 8);
        half8 v1 = *(const half8*)(VWh + (size_t)eIdx[1][n] * HH + ho * 8);
        half8 v2 = *(const half8*)(VWh + (size_t)eIdx[2][n] * HH + ho * 8);
        half8 p = rw * v0;
        p = p * v1;
        p = p * v2;
#pragma unroll
        for (int k = 0; k < 8; ++k) acc8[k] += (float)p[k];
    }

    // combine the 4 neighbor sub-slots (lane quarters share ho)
#pragma unroll
    for (int k = 0; k < 8; ++k) {
        acc8[k] += __shfl_xor(acc8[k], 16);
        acc8[k] += __shfl_xor(acc8[k], 32);
    }

    if (wv > 0 && lane < 16) {
        partial[wv - 1][ho][0] = make_float4(acc8[0], acc8[1], acc8[2], acc8[3]);
        partial[wv - 1][ho][1] = make_float4(acc8[4], acc8[5], acc8[6], acc8[7]);
    }
    __syncthreads();
    if (wv == 0 && lane < 16) {
        float4 s0 = make_float4(acc8[0], acc8[1], acc8[2], acc8[3]);
        float4 s1 = make_float4(acc8[4], acc8[5], acc8[6], acc8[7]);
#pragma unroll
        for (int g = 0; g < 3; ++g) {
            float4 t0 = partial[g][ho][0], t1 = partial[g][ho][1];
            s0.x += t0.x; s0.y += t0.y; s0.z += t0.z; s0.w += t0.w;
            s1.x += t1.x; s1.y += t1.y; s1.z += t1.z; s1.w += t1.w;
        }
        float4 p0 = ((const float4*)peProd)[ho * 2];
        float4 p1 = ((const float4*)peProd)[ho * 2 + 1];
        ((float4*)(out + (size_t)b * HH))[ho * 2] =
            make_float4(s0.x * p0.x, s0.y * p0.y, s0.z * p0.z, s0.w * p0.w);
        ((float4*)(out + (size_t)b * HH))[ho * 2 + 1] =
            make_float4(s1.x * p1.x, s1.y * p1.y, s1.z * p1.z, s1.w * p1.w);
    }
}

// ---------------- Launch -----------------------------------------------------
extern "C" void kernel_launch(void* const* d_in, const int* in_sizes, int n_in,
                              void* d_out, int out_size, void* d_ws, size_t ws_size,
                              hipStream_t stream) {
    const int* r = (const int*)d_in[0];
    const int* e = (const int*)d_in[1];
    const float* V = (const float*)d_in[2];
    const float* R = (const float*)d_in[3];
    const float* P = (const float*)d_in[4];
    const float* WV = (const float*)d_in[5];
    const float* bV = (const float*)d_in[6];
    const float* WR = (const float*)d_in[7];
    const float* bR = (const float*)d_in[8];
    const float* WP = (const float*)d_in[9];
    const float* bP = (const float*)d_in[10];
    float* out = (float*)d_out;

    // ws layout: VWh [NUM_V,H] fp16 | RWh [NUM_R,H] fp16 | peProd [H] f32 | Wfrag 48 KB (f16)
    _Float16* VWh = (_Float16*)d_ws;
    _Float16* RWh = VWh + (size_t)NUM_V * HH;
    float* peProd = (float*)(RWh + (size_t)NUM_R * HH);
    unsigned short* wfrag = (unsigned short*)(peProd + HH);

    prep_kernel<<<81, 256, 0, stream>>>(R, WR, bR, RWh, WV, wfrag, P, WP, bP, peProd);
    gemm_bres<<<512, 832, 0, stream>>>(V, wfrag, bV, VWh, NUM_V);
    gather_kernel<<<BB, 256, 0, stream>>>(r, e, VWh, RWh, peProd, out);
}